// Round 1
// baseline (215.942 us; speedup 1.0000x reference)
//
#include <hip/hip_runtime.h>

// Problem constants
#define B_ 256
#define T_ 64
#define N_ 128
#define H_ 128
#define G3 384   // 3*H (gate rows)
#define K2 256   // 2*H (packed matvec K range: [agg ; prev])

// Workspace layout (float offsets)
#define WS_G    0                    // G table: 384*384
#define WS_PW   (WS_G + G3*G3)       // packed transposed weights: 256*384
#define WS_WLT  (WS_PW + K2*G3)      // W_ih left transposed: 128*384
#define WS_NZC  (WS_WLT + H_*G3)     // 128 ints: nonzero counts
#define WS_NZP  (WS_NZC + 128)       // 128*128 int2 pairs (n, w bits)

// ---------------------------------------------------------------------------
// Kernel A: build PW[k][j] (k<128: W_ih[j][128+k], else W_hh[j][k-128]) and
//           WLT[k][j] = W_ih[j][k]  (transposes for coalesced reads)
// ---------------------------------------------------------------------------
__global__ void build_mats(const float* __restrict__ W_ih,
                           const float* __restrict__ W_hh,
                           float* __restrict__ ws) {
    float* PW  = ws + WS_PW;
    float* WLT = ws + WS_WLT;
    int idx = blockIdx.x * blockDim.x + threadIdx.x;
    const int total_pw = K2 * G3;
    if (idx < total_pw) {
        int k = idx / G3, j = idx % G3;
        PW[idx] = (k < H_) ? W_ih[j * K2 + H_ + k] : W_hh[j * H_ + (k - H_)];
    } else {
        int idx2 = idx - total_pw;
        if (idx2 < H_ * G3) {
            int k = idx2 / G3, j = idx2 % G3;
            WLT[idx2] = W_ih[j * K2 + k];
        }
    }
}

// ---------------------------------------------------------------------------
// Kernel B: G[e][j] = b_ih[j] + sum_k W_ih[j][k] * emb[e][k]   (e in [0,384))
// ---------------------------------------------------------------------------
__global__ void build_G(const float* __restrict__ emb,
                        const float* __restrict__ b_ih,
                        float* __restrict__ ws) {
    __shared__ float es[H_];
    const float* WLT = ws + WS_WLT;
    float* G = ws + WS_G;
    const int e = blockIdx.x;
    const int j = threadIdx.x;              // blockDim = 384
    if (j < H_) es[j] = emb[e * H_ + j];
    __syncthreads();
    float acc = b_ih[j];
    #pragma unroll 8
    for (int k = 0; k < H_; ++k) acc += WLT[k * G3 + j] * es[k];
    G[e * G3 + j] = acc;
}

// ---------------------------------------------------------------------------
// Kernel C: per-row nonzero lists of adj (ascending n, padded to multiple of 4)
// ---------------------------------------------------------------------------
__global__ void build_nz(const float* __restrict__ adj, float* __restrict__ ws) {
    __shared__ float row[N_];
    const int r = blockIdx.x;               // 128 blocks, 128 threads
    row[threadIdx.x] = adj[r * N_ + threadIdx.x];
    __syncthreads();
    if (threadIdx.x == 0) {
        int*  nzc = (int*)(ws + WS_NZC);
        int2* nzp = (int2*)(ws + WS_NZP);
        int cnt = 0;
        for (int n = 0; n < N_; ++n) {
            float w = row[n];
            if (w != 0.0f) { nzp[r * N_ + cnt] = make_int2(n, __float_as_int(w)); ++cnt; }
        }
        int cnt4 = (cnt + 3) & ~3;
        for (int i = cnt; i < cnt4; ++i) nzp[r * N_ + i] = make_int2(0, 0); // w=0 pad
        nzc[r] = cnt;
    }
}

// ---------------------------------------------------------------------------
// Main kernel: one block per batch element, full T-step recurrence.
// 512 threads = (t in [0,128)) x (q in [0,4)).
// Thread (t,q) owns gate rows {t, 128+t, 256+t} restricted to k in [64q,64q+64),
// with those 192 weights held in VGPRs for the whole kernel.
// ---------------------------------------------------------------------------
__global__ void __launch_bounds__(512) gkt_main(
        const int* __restrict__ task_seq, const int* __restrict__ status_seq,
        const float* __restrict__ b_hh,   const float* __restrict__ w_pred,
        const float* __restrict__ b_pred, const float* __restrict__ ws,
        float* __restrict__ out) {
    __shared__ __align__(16) float h_lds[N_ * H_];   // 64 KB state
    __shared__ float4 vbuf4[K2 / 4];                 // [agg(128) ; prev(128)]
    __shared__ float  pl[4 * G3];                    // matvec partials [q][gate*128+t]
    __shared__ float  red[H_];                       // logit-dot partials
    __shared__ float  Ll[N_];                        // running logits
    __shared__ int2   nzl[2][N_];                    // double-buffered nz list
    __shared__ int    nzc_l[2];

    const int b   = blockIdx.x;
    const int tid = threadIdx.x;
    const int t   = tid & 127;
    const int q   = tid >> 7;

    const float* G   = ws + WS_G;
    const float* PW  = ws + WS_PW;
    const int*   nzc = (const int*)(ws + WS_NZC);
    const int2*  nzp = (const int2*)(ws + WS_NZP);

    // ---- prologue: register-resident weights (coalesced: lane stride 1 in j)
    float wr[64], wz[64], wn[64];
    {
        const float* base = PW + (q * 64) * G3 + t;
        #pragma unroll
        for (int kk = 0; kk < 64; ++kk) {
            wr[kk] = base[kk * G3];
            wz[kk] = base[kk * G3 + 128];
            wn[kk] = base[kk * G3 + 256];
        }
    }
    const float bp = b_pred[0];
    float bhr = 0.f, bhz = 0.f, bhn = 0.f, wpt = 0.f;
    if (q == 0) { bhr = b_hh[t]; bhz = b_hh[128 + t]; bhn = b_hh[256 + t]; wpt = w_pred[t]; }

    // ---- init state
    for (int i = tid; i < N_ * H_; i += 512) h_lds[i] = 0.0f;
    if (tid < N_) Ll[tid] = bp;                      // h0=0 -> logits = b_pred
    if (q == 1) {                                    // stage nz list for step 0
        int t0 = task_seq[b * T_];
        nzl[0][t] = nzp[t0 * N_ + t];
        if (t == 0) nzc_l[0] = nzc[t0];
    }
    __syncthreads();

    float* vb = (float*)vbuf4;

    for (int s = 0; s < T_; ++s) {
        const int cur = s & 1, nxt = cur ^ 1;
        const int task = task_seq[b * T_ + s];
        const int stat = status_seq[b * T_ + s];
        float g0 = 0.f, g1 = 0.f, g2 = 0.f;

        // ---- P1: sparse agg (q0), stage prev (q1), store prev-step logits (q2)
        if (q == 0) {
            const int e = task * 3 + stat;
            g0 = G[e * G3 + t];                      // prefetch G row (used in P3)
            g1 = G[e * G3 + 128 + t];
            g2 = G[e * G3 + 256 + t];
            float acc = 0.0f;
            const int cnt4 = (nzc_l[cur] + 3) & ~3;
            for (int i = 0; i < cnt4; i += 4) {
                int2 p0 = nzl[cur][i + 0], p1 = nzl[cur][i + 1];
                int2 p2 = nzl[cur][i + 2], p3 = nzl[cur][i + 3];
                acc += __int_as_float(p0.y) * h_lds[p0.x * H_ + t];
                acc += __int_as_float(p1.y) * h_lds[p1.x * H_ + t];
                acc += __int_as_float(p2.y) * h_lds[p2.x * H_ + t];
                acc += __int_as_float(p3.y) * h_lds[p3.x * H_ + t];
            }
            vb[t] = acc;
        } else if (q == 1) {
            vb[128 + t] = h_lds[task * H_ + t];      // prev state
        } else if (q == 2) {
            if (s > 0) out[(size_t)b * T_ * N_ + (size_t)(s - 1) * N_ + t] = Ll[t];
        }
        __syncthreads();

        // ---- P2: matvec, all 512 threads, weights from registers
        {
            float pr = 0.f, pz = 0.f, pn = 0.f;
            const float* vq = vb + q * 64;
            #pragma unroll
            for (int kk = 0; kk < 64; kk += 4) {
                const float4 v = *(const float4*)(vq + kk);   // wave-uniform LDS read
                pr += wr[kk] * v.x + wr[kk + 1] * v.y + wr[kk + 2] * v.z + wr[kk + 3] * v.w;
                pz += wz[kk] * v.x + wz[kk + 1] * v.y + wz[kk + 2] * v.z + wz[kk + 3] * v.w;
                pn += wn[kk] * v.x + wn[kk + 1] * v.y + wn[kk + 2] * v.z + wn[kk + 3] * v.w;
            }
            pl[q * G3 + t]       = pr;
            pl[q * G3 + 128 + t] = pz;
            pl[q * G3 + 256 + t] = pn;
        }
        __syncthreads();

        // ---- P3: gates + state update (q0); stage next nz list (q1)
        if (q == 0) {
            float sr = g0 + bhr + pl[0*G3 + t] + pl[1*G3 + t] + pl[2*G3 + t] + pl[3*G3 + t];
            float sz = g1 + bhz + pl[0*G3 + 128 + t] + pl[1*G3 + 128 + t]
                                + pl[2*G3 + 128 + t] + pl[3*G3 + 128 + t];
            float in_ = g2 + pl[0*G3 + 256 + t] + pl[1*G3 + 256 + t];   // i_n (k<128)
            float hn_ = bhn + pl[2*G3 + 256 + t] + pl[3*G3 + 256 + t];  // h_n (k>=128)
            float r = 1.0f / (1.0f + expf(-sr));
            float z = 1.0f / (1.0f + expf(-sz));
            float n = tanhf(in_ + r * hn_);
            float prev = h_lds[task * H_ + t];
            float hnew = (1.0f - z) * n + z * prev;
            h_lds[task * H_ + t] = hnew;
            red[t] = hnew * wpt;
        } else if (q == 1) {
            if (s + 1 < T_) {
                int tn = task_seq[b * T_ + s + 1];
                nzl[nxt][t] = nzp[tn * N_ + t];
                if (t == 0) nzc_l[nxt] = nzc[tn];
            }
        }
        __syncthreads();

        // ---- P4: update running logit L[task] = dot(hnew, w_pred) + b_pred
        if (tid < 64) {
            float x = red[tid] + red[tid + 64];
            #pragma unroll
            for (int off = 32; off > 0; off >>= 1) x += __shfl_xor(x, off, 64);
            if (tid == 0) Ll[task] = x + bp;
        }
        __syncthreads();
    }

    // ---- epilogue: last logits row + final hidden state
    if (q == 2) out[(size_t)b * T_ * N_ + (size_t)(T_ - 1) * N_ + t] = Ll[t];
    {
        float4* dst = (float4*)(out + (size_t)B_ * T_ * N_ + (size_t)b * N_ * H_);
        const float4* src = (const float4*)h_lds;
        for (int i = tid; i < N_ * H_ / 4; i += 512) dst[i] = src[i];
    }
}

// ---------------------------------------------------------------------------
extern "C" void kernel_launch(void* const* d_in, const int* in_sizes, int n_in,
                              void* d_out, int out_size, void* d_ws, size_t ws_size,
                              hipStream_t stream) {
    const int*   task = (const int*)d_in[0];
    const int*   stat = (const int*)d_in[1];
    const float* adj  = (const float*)d_in[2];
    const float* emb  = (const float*)d_in[3];
    const float* Wih  = (const float*)d_in[4];
    const float* Whh  = (const float*)d_in[5];
    const float* bih  = (const float*)d_in[6];
    const float* bhh  = (const float*)d_in[7];
    const float* wp   = (const float*)d_in[8];
    const float* bp   = (const float*)d_in[9];
    float* out = (float*)d_out;
    float* ws  = (float*)d_ws;

    // total elements for build_mats = 256*384 + 128*384 = 147456 = 576 * 256
    build_mats<<<576, 256, 0, stream>>>(Wih, Whh, ws);
    build_G  <<<384, 384, 0, stream>>>(emb, bih, ws);
    build_nz <<<128, 128, 0, stream>>>(adj, ws);
    gkt_main <<<256, 512, 0, stream>>>(task, stat, bhh, wp, bp, ws, out);
}